// Round 4
// baseline (77.629 us; speedup 1.0000x reference)
//
#include <hip/hip_runtime.h>

#define EPSF 1e-6f
#define Bsz 2
#define Tn  512
#define En  1024
#define Hn  256
#define Mtot (Bsz * Tn)          // 1024 rows
typedef unsigned short us_t;
typedef unsigned int   u32_t;

typedef __attribute__((ext_vector_type(8))) short bf16x8;
typedef __attribute__((ext_vector_type(4))) float f32x4;
#define MFMA16(a, b, c) __builtin_amdgcn_mfma_f32_16x16x32_bf16((a), (b), (c), 0, 0, 0)

// ---------------------------------------------------------------------------
__device__ __forceinline__ us_t f2bf(float f) {
  union { float f; u32_t u; } x; x.f = f;
  u32_t r = (x.u + 0x7fffu + ((x.u >> 16) & 1u)) >> 16;   // RNE
  return (us_t)r;
}
__device__ __forceinline__ float bf2f(us_t u) {
  union { u32_t u; float f; } x; x.u = ((u32_t)u) << 16; return x.f;
}
__device__ __forceinline__ uint2 pack4bf(float a, float b, float c, float d) {
  uint2 r;
  r.x = (u32_t)f2bf(a) | ((u32_t)f2bf(b) << 16);
  r.y = (u32_t)f2bf(c) | ((u32_t)f2bf(d) << 16);
  return r;
}
__device__ __forceinline__ float block_reduce_sum_256(float v, float* smem) {
  #pragma unroll
  for (int off = 32; off > 0; off >>= 1) v += __shfl_down(v, off, 64);
  const int wave = threadIdx.x >> 6;
  if ((threadIdx.x & 63) == 0) smem[wave] = v;
  __syncthreads();
  float s = smem[0] + smem[1] + smem[2] + smem[3];
  __syncthreads();
  return s;
}

// ---------------------------------------------------------------------------
// K0 (fused prep): blocks 0..1023: xb=bf16(x), rs=rsqrt(mean(x^2)+eps).
//                  blocks 1024..1791: transpose+cast w1,w2,w3.
// ---------------------------------------------------------------------------
__global__ __launch_bounds__(256) void k_prep(
    const float* __restrict__ x,
    const float* __restrict__ w1, const float* __restrict__ w2,
    const float* __restrict__ w3,
    us_t* __restrict__ xb, float* __restrict__ rs,
    us_t* __restrict__ w1t, us_t* __restrict__ w2t, us_t* __restrict__ w3t)
{
  __shared__ float red[4];
  __shared__ float ts[32][33];
  const int b = blockIdx.x, t = threadIdx.x;

  if (b < 1024) {
    float4 v = ((const float4*)(x + (size_t)b * En))[t];
    float ss = block_reduce_sum_256(v.x*v.x + v.y*v.y + v.z*v.z + v.w*v.w, red);
    if (t == 0) rs[b] = rsqrtf(ss * (1.0f / En) + EPSF);
    ((uint2*)(xb + (size_t)b * En))[t] = pack4bf(v.x, v.y, v.z, v.w);
    return;
  }

  const int i = b - 1024;
  const float* src; us_t* dst; int R, C, tr, tc;
  if (i < 256)      { src = w1; dst = w1t; R = 1024; C = 256;  tr = i >> 3;  tc = i & 7; }
  else if (i < 512) { int k = i - 256; src = w2; dst = w2t; R = 1024; C = 256; tr = k >> 3; tc = k & 7; }
  else              { int k = i - 512; src = w3; dst = w3t; R = 256; C = 1024; tr = k >> 5; tc = k & 31; }

  const int r = t >> 3, c4 = (t & 7) * 4;
  float4 v = *(const float4*)(src + (size_t)(tr * 32 + r) * C + tc * 32 + c4);
  ts[r][c4 + 0] = v.x; ts[r][c4 + 1] = v.y; ts[r][c4 + 2] = v.z; ts[r][c4 + 3] = v.w;
  __syncthreads();
  float o0 = ts[c4 + 0][r], o1 = ts[c4 + 1][r], o2 = ts[c4 + 2][r], o3 = ts[c4 + 3][r];
  *(uint2*)(dst + (size_t)(tc * 32 + r) * R + tr * 32 + c4) = pack4bf(o0, o1, o2, o3);
}

// ---------------------------------------------------------------------------
// K1: fused a/b GEMM + RMSNorm, no partials buffer.
// 64 blocks x 512 thr.  block: which = b&1, rowgroup rg = b>>1 (32 rows).
// 8 waves = 2 rowhalves x 4 col-quarters; wave tile 16x64, full K=1024.
// Epilogue: accs -> LDS [32][260] f32, block-norm rows, write bf16 A/Bm.
// ---------------------------------------------------------------------------
__global__ __launch_bounds__(512) void k_gemm_ab(
    const us_t* __restrict__ xb,
    const us_t* __restrict__ w1t, const us_t* __restrict__ w2t,
    const float* __restrict__ rs,
    const float* __restrict__ b1, const float* __restrict__ b2,
    us_t* __restrict__ A, us_t* __restrict__ Bm)
{
  const int blk   = blockIdx.x;
  const int which = blk & 1;
  const int m0    = (blk >> 1) * 32;
  const int w     = threadIdx.x >> 6;
  const int lane  = threadIdx.x & 63;
  const int rh    = w >> 2;            // 0..1 rowhalf
  const int nq    = w & 3;             // 0..3 col quarter
  const int n0    = nq * 64;
  const int lg    = lane >> 4, lr = lane & 15;

  const us_t* __restrict__ wt = which ? w2t : w1t;
  const us_t* ap = xb + (size_t)(m0 + rh * 16 + lr) * En + lg * 8;
  const us_t* bp = wt + (size_t)(n0 + lr) * En + lg * 8;

  f32x4 acc[4];
  #pragma unroll
  for (int c = 0; c < 4; ++c) acc[c] = (f32x4){0.f, 0.f, 0.f, 0.f};

  #pragma unroll 4
  for (int s = 0; s < 32; ++s) {
    bf16x8 a = *(const bf16x8*)(ap + s * 32);
    #pragma unroll
    for (int c = 0; c < 4; ++c) {
      bf16x8 bb = *(const bf16x8*)(bp + (size_t)c * 16 * En + s * 32);
      acc[c] = MFMA16(a, bb, acc[c]);
    }
  }

  __shared__ float sv[32][260];
  #pragma unroll
  for (int c = 0; c < 4; ++c)
    #pragma unroll
    for (int i = 0; i < 4; ++i)
      sv[rh * 16 + lg * 4 + i][n0 + c * 16 + lr] = acc[c][i];
  __syncthreads();

  // norm phase: thread t -> row = t>>4 (0..31), seg = t&15 (16 cols each)
  const int row = threadIdx.x >> 4, seg = threadIdx.x & 15;
  const float rscale = rs[m0 + row];
  const float* __restrict__ bias = which ? b2 : b1;
  float v[16]; float ss = 0.f;
  #pragma unroll
  for (int k = 0; k < 16; ++k) {
    float val = sv[row][seg * 16 + k] * rscale + bias[seg * 16 + k];
    v[k] = val; ss += val * val;
  }
  #pragma unroll
  for (int off = 1; off < 16; off <<= 1) ss += __shfl_xor(ss, off, 64);
  const float sc = rsqrtf(ss * (1.0f / Hn) + EPSF);

  us_t* outp = (which ? Bm : A) + (size_t)(m0 + row) * Hn + seg * 16;
  #pragma unroll
  for (int k = 0; k < 4; ++k)
    ((uint2*)outp)[k] = pack4bf(v[4*k] * sc, v[4*k+1] * sc, v[4*k+2] * sc, v[4*k+3] * sc);
}

// ---------------------------------------------------------------------------
// K2: causal relu prefix + fused RMSNorm.  ITILE=2, 512 blocks.
// Load-balance remap: raw<256 -> tile raw (batch 0), else tile 511-raw
// (batch 1): CU c's two blocks sum to constant work.
// ---------------------------------------------------------------------------
#define ITILE 2
#define JCH   16
__global__ __launch_bounds__(256) void k_bar(
    const us_t* __restrict__ A, const us_t* __restrict__ Bm,
    us_t* __restrict__ Yb)
{
  const int raw  = blockIdx.x;
  const int sel  = (raw < 256) ? raw : (511 - raw);
  const int bb   = raw >> 8;
  const int i0   = sel * ITILE;
  const int h    = threadIdx.x;
  const size_t base = (size_t)bb * Tn * Hn;
  const us_t* __restrict__ bp = Bm + base + h;

  float av[ITILE], sum[ITILE];
  #pragma unroll
  for (int r = 0; r < ITILE; ++r) {
    av[r]  = bf2f(A[base + (size_t)(i0 + r) * Hn + h]);
    sum[r] = 0.f;
  }

  const int nfull = i0 & ~(JCH - 1);
  us_t b0[JCH], b1[JCH];

  #define LOADCH(buf, jj) { _Pragma("unroll") \
    for (int tt = 0; tt < JCH; ++tt) buf[tt] = bp[(size_t)((jj) + tt) * Hn]; }
  #define COMPCH(buf) { _Pragma("unroll") \
    for (int tt = 0; tt < JCH; ++tt) { float bv = bf2f(buf[tt]); _Pragma("unroll") \
      for (int r = 0; r < ITILE; ++r) sum[r] += fmaxf(av[r] + bv, 0.f); } }

  if (nfull > 0) {
    LOADCH(b0, 0);
    int j = 0;
    while (true) {
      const bool more1 = (j + JCH     < nfull);
      const bool more2 = (j + 2 * JCH < nfull);
      if (more1) LOADCH(b1, j + JCH);
      COMPCH(b0);
      j += JCH;
      if (!more1) break;
      if (more2) LOADCH(b0, j + JCH);
      COMPCH(b1);
      j += JCH;
      if (!more2) break;
    }
  }
  { // fixed-width predicated tail (in-bounds: nfull+15 <= 511)
    us_t bt[JCH];
    LOADCH(bt, nfull);
    const int lim = i0 - nfull;
    #pragma unroll
    for (int tt = 0; tt < JCH; ++tt) {
      float bv = bf2f(bt[tt]);
      #pragma unroll
      for (int r = 0; r < ITILE; ++r)
        sum[r] += (tt <= lim + r) ? fmaxf(av[r] + bv, 0.f) : 0.f;
    }
  }
  #undef LOADCH
  #undef COMPCH

  __shared__ float red[4];
  #pragma unroll
  for (int r = 0; r < ITILE; ++r) {
    float ss = block_reduce_sum_256(sum[r] * sum[r], red);
    float c  = (float)(i0 + r + 1);
    float sc = rsqrtf(ss * (1.0f / Hn) + EPSF * c * c);
    Yb[base + (size_t)(i0 + r) * Hn + h] = f2bf(sum[r] * sc);
  }
}

// ---------------------------------------------------------------------------
// K3: out = x + Ynorm @ w3 + b3.  MFMA, LDS-free.  Wave tile 32x32, K=256.
// 256 blocks x 4 waves = 1024 waves = 32 mt x 32 nt.
// ---------------------------------------------------------------------------
__global__ __launch_bounds__(256) void k_out(
    const us_t* __restrict__ Yb, const us_t* __restrict__ w3t,
    const float* __restrict__ x, const float* __restrict__ b3,
    float* __restrict__ out)
{
  const int wid = threadIdx.x >> 6, lane = threadIdx.x & 63;
  const int wg = blockIdx.x * 4 + wid;
  const int nt = wg & 31, mt = wg >> 5;
  const int m0 = mt * 32, n0 = nt * 32;
  const int lg = lane >> 4, lr = lane & 15;

  const us_t* ap0 = Yb  + (size_t)(m0 + lr) * Hn + lg * 8;
  const us_t* ap1 = ap0 + 16 * Hn;
  const us_t* bp0 = w3t + (size_t)(n0 + lr) * Hn + lg * 8;
  const us_t* bp1 = bp0 + 16 * Hn;

  f32x4 acc00 = {0.f,0.f,0.f,0.f}, acc01 = acc00, acc10 = acc00, acc11 = acc00;

  #pragma unroll 4
  for (int s = 0; s < 8; ++s) {
    bf16x8 a0 = *(const bf16x8*)(ap0 + s * 32);
    bf16x8 a1 = *(const bf16x8*)(ap1 + s * 32);
    bf16x8 b0 = *(const bf16x8*)(bp0 + s * 32);
    bf16x8 b1 = *(const bf16x8*)(bp1 + s * 32);
    acc00 = MFMA16(a0, b0, acc00);
    acc01 = MFMA16(a0, b1, acc01);
    acc10 = MFMA16(a1, b0, acc10);
    acc11 = MFMA16(a1, b1, acc11);
  }

  const int c0 = n0 + lr, c1 = n0 + 16 + lr;
  const float bv0 = b3[c0], bv1 = b3[c1];
  #pragma unroll
  for (int i = 0; i < 4; ++i) {
    const int r0 = m0 + lg * 4 + i, r1 = r0 + 16;
    const size_t o00 = (size_t)r0 * En + c0, o01 = (size_t)r0 * En + c1;
    const size_t o10 = (size_t)r1 * En + c0, o11 = (size_t)r1 * En + c1;
    out[o00] = x[o00] + acc00[i] + bv0;
    out[o01] = x[o01] + acc01[i] + bv1;
    out[o10] = x[o10] + acc10[i] + bv0;
    out[o11] = x[o11] + acc11[i] + bv1;
  }
}

// ---------------------------------------------------------------------------
extern "C" void kernel_launch(void* const* d_in, const int* in_sizes, int n_in,
                              void* d_out, int out_size, void* d_ws, size_t ws_size,
                              hipStream_t stream) {
  const float* x  = (const float*)d_in[0];
  const float* w1 = (const float*)d_in[1];
  const float* b1 = (const float*)d_in[2];
  const float* w2 = (const float*)d_in[3];
  const float* b2 = (const float*)d_in[4];
  const float* w3 = (const float*)d_in[5];
  const float* b3 = (const float*)d_in[6];
  float* out = (float*)d_out;

  char* p = (char*)d_ws;
  us_t* xb   = (us_t*)p;                p += (size_t)Mtot * En * 2;       // 2 MB
  us_t* w1t  = (us_t*)p;                p += (size_t)Hn * En * 2;
  us_t* w2t  = (us_t*)p;                p += (size_t)Hn * En * 2;
  us_t* w3t  = (us_t*)p;                p += (size_t)En * Hn * 2;
  us_t* A    = (us_t*)p;                p += (size_t)Mtot * Hn * 2;
  us_t* Bm   = (us_t*)p;                p += (size_t)Mtot * Hn * 2;
  us_t* Yb   = (us_t*)p;                p += (size_t)Mtot * Hn * 2;
  float* rs  = (float*)p;               p += (size_t)Mtot * 4;

  k_prep    <<<1792, 256, 0, stream>>>(x, w1, w2, w3, xb, rs, w1t, w2t, w3t);
  k_gemm_ab <<<64,   512, 0, stream>>>(xb, w1t, w2t, rs, b1, b2, A, Bm);
  k_bar     <<<512,  256, 0, stream>>>(A, Bm, Yb);
  k_out     <<<256,  256, 0, stream>>>(Yb, w3t, x, b3, out);
}